// Round 14
// baseline (267.181 us; speedup 1.0000x reference)
//
#include <hip/hip_runtime.h>
#include <hip/hip_bf16.h>
#include <math.h>

#define HW_ (192*192)
#define Wd 192
#define HIDc 127
#define NBLK1 (HW_/64)   // 576 ln1qkv blocks

// fp32 weight-copy offsets inside ws "wts" region
#define O_LN1W 0
#define O_QKVW 96
#define O_QKVB 7008
#define O_RPB  7152
#define O_PROJW 7490
#define O_PROJB 9794
#define O_ECA  9842
#define O_LN2W 9849
#define O_WIN  9945
#define O_WDW  22137
#define O_WOUT 24423
#define WTS_LEN 30519

typedef unsigned short ushort_t;

__device__ __forceinline__ float b2f(__hip_bfloat16 v){ return __bfloat162float(v); }
__device__ __forceinline__ float u2f(ushort_t h){ return __uint_as_float(((unsigned)h)<<16); }
__device__ __forceinline__ ushort_t f2u(float f){
    __hip_bfloat16 h = __float2bfloat16(f);
    union { __hip_bfloat16 b; ushort_t u; } c; c.b = h; return c.u;
}
// unpack packed 2xbf16 (low index in low 16 bits)
__device__ __forceinline__ void up2(unsigned u, float& a, float& b){
    a = __uint_as_float(u << 16);
    b = __uint_as_float(u & 0xffff0000u);
}

__device__ __forceinline__ int wstart(int i){
    // L=192, K=7, DIL=3 closed form of _window_starts
    if (i < 9) return i % 3;
    if (i >= 183) return 171 + (i % 3);
    return i - 9;
}

// bf16 row (48 elems, 6 uint4) dot fp32 vec[48]
__device__ __forceinline__ float dot48bf(const uint4* wr, const float* xr){
    float acc = 0.f;
    #pragma unroll
    for (int c8 = 0; c8 < 6; c8++){
        uint4 u = wr[c8];
        float f0,f1,f2,f3,f4,f5,f6,f7;
        up2(u.x,f0,f1); up2(u.y,f2,f3); up2(u.z,f4,f5); up2(u.w,f6,f7);
        acc += f0*xr[8*c8]   + f1*xr[8*c8+1] + f2*xr[8*c8+2] + f3*xr[8*c8+3]
             + f4*xr[8*c8+4] + f5*xr[8*c8+5] + f6*xr[8*c8+6] + f7*xr[8*c8+7];
    }
    return acc;
}

// ------------- Kernel B: convert weights (self-detecting dtype) -----------------
__global__ void convert_kernel(
    const void* p0, const void* p1, const void* p2, const void* p3,
    const void* p4, const void* p5, const void* p6, const void* p7,
    const void* p8, const void* p9, const void* p10, const void* p11,
    const void* p12, const ushort_t* __restrict__ xu, int* __restrict__ mode_out,
    float* __restrict__ wts, ushort_t* __restrict__ qkvbf, float* __restrict__ woutT,
    ushort_t* __restrict__ winbf, ushort_t* __restrict__ projbf)
{
    __shared__ int sbad;
    if (threadIdx.x == 0) sbad = 0;
    __syncthreads();
    {   // 256-sample dtype sniff on x: bf16 N(0,1) never has |v|>=100
        unsigned u = xu[2*threadIdx.x];
        float f = __uint_as_float(u << 16);
        if (!(fabsf(f) < 100.f)) atomicAdd(&sbad, 1);
    }
    __syncthreads();
    const int md = (sbad > 16) ? 1 : 0;
    if (blockIdx.x == 0 && threadIdx.x == 0) mode_out[0] = md;

    const void* ps[13] = {p0,p1,p2,p3,p4,p5,p6,p7,p8,p9,p10,p11,p12};
    const int sz[13]  = {48,48,6912,144,338,2304,48,7,48,48,12192,2286,6096};
    const int off[13] = {O_LN1W,48,O_QKVW,O_QKVB,O_RPB,O_PROJW,O_PROJB,O_ECA,
                         O_LN2W,9897,O_WIN,O_WDW,O_WOUT};
    int b = blockIdx.x;
    if (b >= 13){
        // bf16-packed copies: 13=qkv_w, 14=woutT, 15=w_in, 16=proj_w
        if (b == 13){
            if (md){
                const float* s = (const float*)p2;
                for (int i = threadIdx.x; i < 6912; i += 256) qkvbf[i] = f2u(s[i]);
            } else {
                const ushort_t* s = (const ushort_t*)p2;
                for (int i = threadIdx.x; i < 6912; i += 256) qkvbf[i] = s[i];
            }
        } else if (b == 14){
            if (md){
                const float* s = (const float*)p12;
                for (int i = threadIdx.x; i < 6096; i += 256){
                    int c = i / 48, o = i - c*48;
                    woutT[i] = s[o*127 + c];
                }
            } else {
                const __hip_bfloat16* s = (const __hip_bfloat16*)p12;
                for (int i = threadIdx.x; i < 6096; i += 256){
                    int c = i / 48, o = i - c*48;
                    woutT[i] = b2f(s[o*127 + c]);
                }
            }
        } else if (b == 15){
            if (md){
                const float* s = (const float*)p10;
                for (int i = threadIdx.x; i < 12192; i += 256) winbf[i] = f2u(s[i]);
            } else {
                const ushort_t* s = (const ushort_t*)p10;
                for (int i = threadIdx.x; i < 12192; i += 256) winbf[i] = s[i];
            }
        } else {
            if (md){
                const float* s = (const float*)p5;
                for (int i = threadIdx.x; i < 2304; i += 256) projbf[i] = f2u(s[i]);
            } else {
                const ushort_t* s = (const ushort_t*)p5;
                for (int i = threadIdx.x; i < 2304; i += 256) projbf[i] = s[i];
            }
        }
        return;
    }
    int n = sz[b];
    float* dst = wts + off[b];
    if (md){
        const float* s = (const float*)ps[b];
        for (int i = threadIdx.x; i < n; i += 256) dst[i] = s[i];
    } else {
        const __hip_bfloat16* s = (const __hip_bfloat16*)ps[b];
        for (int i = threadIdx.x; i < n; i += 256) dst[i] = b2f(s[i]);
    }
}

// ------------- Kernel 1: LN1 + QKV proj + ECA partials --------------------------
// 576 blocks x 384 thr = 64 px * 6 wave-uniform r-groups (24 outputs each).
__global__ __launch_bounds__(384) void ln1qkv_kernel(
    const void* __restrict__ x, const int* __restrict__ mode,
    const float* __restrict__ wts, const ushort_t* __restrict__ qkvbf,
    ushort_t* __restrict__ q, ushort_t* __restrict__ k, ushort_t* __restrict__ v,
    float* __restrict__ chpart)
{
    __shared__ float sx[64*49];           // 12544 B

    const int tid  = threadIdx.x;
    const int px_l = tid & 63;
    const int r6   = __builtin_amdgcn_readfirstlane(tid >> 6);  // 0..5 wave-uniform
    const int p0   = blockIdx.x * 64;
    const int p    = p0 + px_l;

    // x tile load, planar-coalesced
    if (mode[0]){
        const float* xf = (const float*)x;
        for (int idx = tid; idx < 64*48; idx += 384){
            int c = idx >> 6, pl = idx & 63;
            sx[pl*49 + c] = xf[c*HW_ + p0 + pl];
        }
    } else {
        const __hip_bfloat16* xb = (const __hip_bfloat16*)x;
        for (int idx = tid; idx < 64*48; idx += 384){
            int c = idx >> 6, pl = idx & 63;
            sx[pl*49 + c] = b2f(xb[c*HW_ + p0 + pl]);
        }
    }
    __syncthreads();

    float xr[48];
    float mu = 0.f;
    #pragma unroll
    for (int c = 0; c < 48; c++){ xr[c] = sx[px_l*49 + c]; mu += xr[c]; }
    mu *= (1.f/48.f);
    float var = 0.f;
    #pragma unroll
    for (int c = 0; c < 48; c++){ float d = xr[c]-mu; var += d*d; }
    var *= (1.f/48.f);
    float rs = rsqrtf(var + 1e-5f);
    #pragma unroll
    for (int c = 0; c < 48; c++)
        xr[c] = (xr[c]-mu)*rs*wts[O_LN1W + c] + wts[O_LN1W + 48 + c];  // scalar K$

    // ECA per-block partials: wave 0 has px 0..63 exactly once
    if (tid < 64){
        #pragma unroll
        for (int c = 0; c < 48; c++){
            float s = xr[c];
            s += __shfl_xor(s, 1);  s += __shfl_xor(s, 2);  s += __shfl_xor(s, 4);
            s += __shfl_xor(s, 8);  s += __shfl_xor(s, 16); s += __shfl_xor(s, 32);
            if (tid == 0) chpart[blockIdx.x*48 + c] = s;
        }
    }

    const int rbase = r6 * 24;
    const float scale = (r6 < 2) ? 0.20412414523193154f : 1.0f;
    float ov[24];
    #pragma unroll 4
    for (int ro = 0; ro < 24; ro++){
        int r = rbase + ro;
        float acc = wts[O_QKVB + r]
                  + dot48bf((const uint4*)(qkvbf + r*48), xr);
        ov[ro] = acc * scale;
    }

    unsigned int pk[12];
    #pragma unroll
    for (int d = 0; d < 12; d++)
        pk[d] = (unsigned)f2u(ov[2*d]) | ((unsigned)f2u(ov[2*d+1]) << 16);
    ushort_t* tp = (r6 >> 1) == 0 ? q : ((r6 >> 1) == 1 ? k : v);
    uint4* dst4 = (uint4*)(tp + (size_t)p*48 + (r6 & 1)*24);
    dst4[0] = make_uint4(pk[0], pk[1], pk[2],  pk[3]);
    dst4[1] = make_uint4(pk[4], pk[5], pk[6],  pk[7]);
    dst4[2] = make_uint4(pk[8], pk[9], pk[10], pk[11]);
}

// ------------- Kernel 2a: parallel partial reduction (48 blocks, 1 per channel) -
__global__ __launch_bounds__(256) void gatered_kernel(
    const float* __restrict__ chpart, float* __restrict__ msum)
{
    __shared__ float red[4];
    const int c = blockIdx.x;          // channel
    const int tid = threadIdx.x;
    float acc = 0.f;
    for (int b = tid; b < NBLK1; b += 256)
        acc += chpart[b*48 + c];
    acc += __shfl_xor(acc, 1);  acc += __shfl_xor(acc, 2);  acc += __shfl_xor(acc, 4);
    acc += __shfl_xor(acc, 8);  acc += __shfl_xor(acc, 16); acc += __shfl_xor(acc, 32);
    if ((tid & 63) == 0) red[tid >> 6] = acc;
    __syncthreads();
    if (tid == 0)
        msum[c] = (red[0] + red[1] + red[2] + red[3]) * (1.f / (float)HW_);
}

// ------------- Kernel 2b: ECA conv1d(k=7,pad=3) -> sigmoid ----------------------
__global__ void gate_kernel(const float* __restrict__ msum,
                            const float* __restrict__ wts,
                            float* __restrict__ gate)
{
    __shared__ float m[48];
    int t = threadIdx.x;
    if (t < 48) m[t] = msum[t];
    __syncthreads();
    if (t < 48){
        float a = 0.f;
        for (int kk = 0; kk < 7; kk++){
            int cc = t + kk - 3;
            if (cc >= 0 && cc < 48) a += wts[O_ECA + kk] * m[cc];
        }
        gate[t] = 1.f / (1.f + expf(-a));
    }
}

// ------------- Kernel 3: neighborhood attention, online softmax -----------------
__global__ __launch_bounds__(256) void attn_kernel(
    const ushort_t* __restrict__ q, const ushort_t* __restrict__ k,
    const ushort_t* __restrict__ v, const float* __restrict__ wts,
    ushort_t* __restrict__ aout)
{
    const int head = blockIdx.y;
    __shared__ float srpb[169];
    for (int i = threadIdx.x; i < 169; i += 256) srpb[i] = wts[O_RPB + head*169 + i];
    __syncthreads();

    const int tid  = threadIdx.x;
    const int px   = blockIdx.x * 128 + (tid >> 1);
    const int half = tid & 1;
    const int i = px / Wd, j = px % Wd;
    const int sti = wstart(i), stj = wstart(j);
    const int pbi = (sti - i) / 3 + 6;
    const int pbj = (stj - j) / 3 + 6;
    const int choff = head*24 + half*12;

    float qr[12];
    {
        const ushort4* qp = (const ushort4*)(q + (size_t)px*48 + choff);
        #pragma unroll
        for (int b = 0; b < 3; b++){
            ushort4 uu = qp[b];
            qr[4*b]   = u2f(uu.x); qr[4*b+1] = u2f(uu.y);
            qr[4*b+2] = u2f(uu.z); qr[4*b+3] = u2f(uu.w);
        }
    }

    float m = -1e30f, s = 0.f;
    float acc[12];
    #pragma unroll
    for (int c = 0; c < 12; c++) acc[c] = 0.f;

    #pragma unroll
    for (int xx = 0; xx < 7; xx++){
        int ii = sti + 3*xx;
        #pragma unroll
        for (int yy = 0; yy < 7; yy++){
            int jj = stj + 3*yy;
            const size_t nb = (size_t)(ii*Wd + jj)*48 + choff;
            const ushort4* kp = (const ushort4*)(k + nb);
            const ushort4* vp = (const ushort4*)(v + nb);
            ushort4 k0 = kp[0], k1 = kp[1], k2 = kp[2];
            ushort4 v0 = vp[0], v1 = vp[1], v2 = vp[2];
            float d = qr[0]*u2f(k0.x) + qr[1]*u2f(k0.y)
                    + qr[2]*u2f(k0.z) + qr[3]*u2f(k0.w)
                    + qr[4]*u2f(k1.x) + qr[5]*u2f(k1.y)
                    + qr[6]*u2f(k1.z) + qr[7]*u2f(k1.w)
                    + qr[8]*u2f(k2.x) + qr[9]*u2f(k2.y)
                    + qr[10]*u2f(k2.z) + qr[11]*u2f(k2.w);
            d += __shfl_xor(d, 1);                         // full 24-ch dot
            float sc = d + srpb[(pbi+xx)*13 + (pbj+yy)];
            float mn = fmaxf(m, sc);
            float corr = __expf(m - mn);
            float p = __expf(sc - mn);
            s = s*corr + p;
            m = mn;
            acc[0]  = acc[0] *corr + p*u2f(v0.x);
            acc[1]  = acc[1] *corr + p*u2f(v0.y);
            acc[2]  = acc[2] *corr + p*u2f(v0.z);
            acc[3]  = acc[3] *corr + p*u2f(v0.w);
            acc[4]  = acc[4] *corr + p*u2f(v1.x);
            acc[5]  = acc[5] *corr + p*u2f(v1.y);
            acc[6]  = acc[6] *corr + p*u2f(v1.z);
            acc[7]  = acc[7] *corr + p*u2f(v1.w);
            acc[8]  = acc[8] *corr + p*u2f(v2.x);
            acc[9]  = acc[9] *corr + p*u2f(v2.y);
            acc[10] = acc[10]*corr + p*u2f(v2.z);
            acc[11] = acc[11]*corr + p*u2f(v2.w);
        }
    }
    const float inv = 1.f / s;
    #pragma unroll
    for (int c = 0; c < 12; c++)
        aout[(size_t)(choff + c)*HW_ + px] = f2u(acc[c] * inv);
}

// ------------- Kernel 4: proj + gate + residual -> x2 (no LDS, no sync) ---------
// 576 blocks x 256 thr = 64 px * 4 wave-uniform o-groups (12 outputs each).
__global__ __launch_bounds__(256) void proj_kernel(
    const ushort_t* __restrict__ aout, const float* __restrict__ wts,
    const ushort_t* __restrict__ projbf, const float* __restrict__ gate,
    const void* __restrict__ x, const int* __restrict__ mode,
    float* __restrict__ x2)
{
    const int tid  = threadIdx.x;
    const int px_l = tid & 63;
    const int og   = __builtin_amdgcn_readfirstlane(tid >> 6);   // 0..3 uniform
    const int px   = blockIdx.x * 64 + px_l;

    float ar[48];
    #pragma unroll
    for (int c = 0; c < 48; c++) ar[c] = u2f(aout[(size_t)c*HW_ + px]);

    const float* xf = (const float*)x;
    const __hip_bfloat16* xb = (const __hip_bfloat16*)x;
    const int md = mode[0];
    const int ob = og * 12;
    #pragma unroll 2
    for (int oo = 0; oo < 12; oo++){
        int o = ob + oo;
        float acc = wts[O_PROJB + o]
                  + dot48bf((const uint4*)(projbf + o*48), ar);
        float res = md ? xf[o*HW_ + px] : b2f(xb[o*HW_ + px]);
        x2[o*HW_ + px] = res + acc * gate[o];
    }
}

// ------------- Kernel 5: LN2 (inline) + pointwise1, y-split for occupancy -------
// grid (576, 2) x 256 thr = 64 px * 4 wave-uniform o-groups * 2 output halves.
// 1152 resident blocks -> ~18 waves/CU; per-y weight slice 12 KB fits K$.
__global__ __launch_bounds__(256) void pw1_kernel(
    const float* __restrict__ x2, const float* __restrict__ wts,
    const ushort_t* __restrict__ winbf, ushort_t* __restrict__ t)
{
    const int tid  = threadIdx.x;
    const int px_l = tid & 63;
    const int og   = __builtin_amdgcn_readfirstlane(tid >> 6);   // 0..3 uniform
    const int px   = blockIdx.x * 64 + px_l;

    float xr[48];
    float mu = 0.f;
    #pragma unroll
    for (int c = 0; c < 48; c++){ xr[c] = x2[c*HW_ + px]; mu += xr[c]; }
    mu *= (1.f/48.f);
    float var = 0.f;
    #pragma unroll
    for (int c = 0; c < 48; c++){ float d = xr[c]-mu; var += d*d; }
    var *= (1.f/48.f);
    float rs = rsqrtf(var + 1e-5f);
    #pragma unroll
    for (int c = 0; c < 48; c++)
        xr[c] = (xr[c]-mu)*rs*wts[O_LN2W + c] + wts[O_LN2W + 48 + c];

    const int base = blockIdx.y * 128 + og * 32;
    for (int t2 = 0; t2 < 32; t2 += 2){
        int o0 = base + t2;
        if (o0 >= 254) break;
        const uint4* wA = (const uint4*)(winbf + o0*48);
        const uint4* wB = (const uint4*)(winbf + min(o0+1,253)*48);
        float accA = 0.f, accB = 0.f;
        #pragma unroll
        for (int c8 = 0; c8 < 6; c8++){
            uint4 ua = wA[c8];
            uint4 ub = wB[c8];
            float a0,a1,a2,a3,a4,a5,a6,a7, b0,b1,b2,b3,b4,b5,b6,b7;
            up2(ua.x,a0,a1); up2(ua.y,a2,a3); up2(ua.z,a4,a5); up2(ua.w,a6,a7);
            up2(ub.x,b0,b1); up2(ub.y,b2,b3); up2(ub.z,b4,b5); up2(ub.w,b6,b7);
            accA += a0*xr[8*c8]   + a1*xr[8*c8+1] + a2*xr[8*c8+2] + a3*xr[8*c8+3]
                  + a4*xr[8*c8+4] + a5*xr[8*c8+5] + a6*xr[8*c8+6] + a7*xr[8*c8+7];
            accB += b0*xr[8*c8]   + b1*xr[8*c8+1] + b2*xr[8*c8+2] + b3*xr[8*c8+3]
                  + b4*xr[8*c8+4] + b5*xr[8*c8+5] + b6*xr[8*c8+6] + b7*xr[8*c8+7];
        }
        t[(size_t)o0*HW_ + px] = f2u(accA);
        if (o0+1 < 254) t[(size_t)(o0+1)*HW_ + px] = f2u(accB);
    }
}

// ------------- Kernel 6: depthwise 3x3 + exact GeLU gating, bf16 in/out ---------
__global__ __launch_bounds__(256) void dw_kernel(
    const ushort_t* __restrict__ t, const float* __restrict__ wts,
    ushort_t* __restrict__ g)
{
    int ch = blockIdx.y;               // 0..126
    int p  = blockIdx.x * 256 + threadIdx.x;
    int i  = p / Wd, j = p % Wd;
    float w1[9], w2[9];
    #pragma unroll
    for (int s = 0; s < 9; s++){
        w1[s] = wts[O_WDW + ch*9 + s];
        w2[s] = wts[O_WDW + (ch+HIDc)*9 + s];
    }
    const ushort_t* t1 = t + (size_t)ch * HW_;
    const ushort_t* t2 = t + (size_t)(ch+HIDc) * HW_;
    float a1 = 0.f, a2 = 0.f;
    #pragma unroll
    for (int di = 0; di < 3; di++){
        int ii = i + di - 1;
        if (ii < 0 || ii >= 192) continue;
        #pragma unroll
        for (int dj = 0; dj < 3; dj++){
            int jj = j + dj - 1;
            if (jj < 0 || jj >= 192) continue;
            int off = ii*Wd + jj;
            a1 += w1[di*3+dj]*u2f(t1[off]);
            a2 += w2[di*3+dj]*u2f(t2[off]);
        }
    }
    float ge = a1 * 0.5f * (1.f + erff(a1 * 0.70710678118654752f)); // exact gelu
    g[(size_t)ch*HW_ + p] = f2u(ge * a2);
}

// ------------- Kernel 7: pointwise2 (woutT scalar-K$) + final residual ----------
__global__ __launch_bounds__(128) void pw2_kernel(
    const ushort_t* __restrict__ g, const float* __restrict__ woutT,
    const float* __restrict__ x2, void* __restrict__ outv,
    const int* __restrict__ mode)
{
    const int ob = blockIdx.y * 12;
    const int p  = blockIdx.x * 128 + threadIdx.x;
    float acc[12];
    #pragma unroll
    for (int o = 0; o < 12; o++) acc[o] = 0.f;
    #pragma unroll 4
    for (int c = 0; c < 127; c++){
        float gv = u2f(g[(size_t)c*HW_ + p]);
        const float* wr = woutT + c*48 + ob;          // uniform -> s_load
        #pragma unroll
        for (int o = 0; o < 12; o++) acc[o] += wr[o]*gv;
    }
    if (mode[0]){
        float* out = (float*)outv;
        #pragma unroll
        for (int o = 0; o < 12; o++){
            int oc = ob + o;
            out[(size_t)oc*HW_ + p] = x2[(size_t)oc*HW_ + p] + acc[o];
        }
    } else {
        __hip_bfloat16* out = (__hip_bfloat16*)outv;
        #pragma unroll
        for (int o = 0; o < 12; o++){
            int oc = ob + o;
            out[(size_t)oc*HW_ + p] =
                __float2bfloat16(x2[(size_t)oc*HW_ + p] + acc[o]);
        }
    }
}

extern "C" void kernel_launch(void* const* d_in, const int* in_sizes, int n_in,
                              void* d_out, int out_size, void* d_ws, size_t ws_size,
                              hipStream_t stream)
{
    (void)in_sizes; (void)n_in; (void)out_size;

    char* ws = (char*)d_ws;
    ushort_t* q    = (ushort_t*)(ws);
    ushort_t* k    = (ushort_t*)(ws + 3538944);
    ushort_t* v    = (ushort_t*)(ws + 7077888);
    ushort_t* aout = (ushort_t*)(ws + 10616832);
    ushort_t* t    = (ushort_t*)(ws);
    float*    x2   = (float*)   (ws + 18726912);
    ushort_t* g    = (ushort_t*)(ws + 25804800);
    float*    gate = (float*)   (ws + 35168448);
    int*      mode = (int*)     (ws + 35168640);
    float*    wts  = (float*)   (ws + 35168656);
    float*    chpart=(float*)   (ws + 35168656 + (size_t)WTS_LEN*4); // [NBLK1][48]
    float*    msum = chpart + (size_t)NBLK1*48;                      // [48]
    ushort_t* qkvbf= (ushort_t*)(msum + 48);                         // [6912] bf16
    float*    woutT= (float*)(qkvbf + 6912);                         // [127*48]
    ushort_t* winbf= (ushort_t*)(woutT + 6096);                      // [12192] bf16
    ushort_t* projbf=(ushort_t*)(winbf + 12192);                     // [2304] bf16

    size_t need = 35168656 + (size_t)WTS_LEN*4 + (size_t)NBLK1*48*4 + 48*4
                + 6912*2 + 6096*4 + 12192*2 + 2304*2;
    if (ws_size < need) return;

    convert_kernel<<<17, 256, 0, stream>>>(
        d_in[1], d_in[2], d_in[3], d_in[4], d_in[5], d_in[6], d_in[7],
        d_in[8], d_in[9], d_in[10], d_in[11], d_in[12], d_in[13],
        (const ushort_t*)d_in[0], mode, wts, qkvbf, woutT, winbf, projbf);

    ln1qkv_kernel<<<dim3(NBLK1), 384, 0, stream>>>(d_in[0], mode, wts, qkvbf,
                                                   q, k, v, chpart);
    gatered_kernel<<<48, 256, 0, stream>>>(chpart, msum);
    gate_kernel<<<1, 64, 0, stream>>>(msum, wts, gate);
    attn_kernel<<<dim3(HW_/128, 2), 256, 0, stream>>>(q, k, v, wts, aout);
    proj_kernel<<<dim3(HW_/64), 256, 0, stream>>>(aout, wts, projbf, gate,
                                                  d_in[0], mode, x2);
    pw1_kernel<<<dim3(HW_/64, 2), 256, 0, stream>>>(x2, wts, winbf, t);
    dw_kernel<<<dim3(HW_/256, 127), 256, 0, stream>>>(t, wts, g);
    pw2_kernel<<<dim3(HW_/128, 4), 128, 0, stream>>>(g, woutT, x2, d_out, mode);
}

// Round 15
// 256.290 us; speedup vs baseline: 1.0425x; 1.0425x over previous
//
#include <hip/hip_runtime.h>
#include <hip/hip_bf16.h>
#include <math.h>

#define HW_ (192*192)
#define Wd 192
#define HIDc 127
#define NBLK1 (HW_/64)   // 576 ln1qkv blocks

// fp32 weight-copy offsets inside ws "wts" region
#define O_LN1W 0
#define O_QKVW 96
#define O_QKVB 7008
#define O_RPB  7152
#define O_PROJW 7490
#define O_PROJB 9794
#define O_ECA  9842
#define O_LN2W 9849
#define O_WIN  9945
#define O_WDW  22137
#define O_WOUT 24423
#define WTS_LEN 30519

typedef unsigned short ushort_t;

__device__ __forceinline__ float b2f(__hip_bfloat16 v){ return __bfloat162float(v); }
__device__ __forceinline__ float u2f(ushort_t h){ return __uint_as_float(((unsigned)h)<<16); }
__device__ __forceinline__ ushort_t f2u(float f){
    __hip_bfloat16 h = __float2bfloat16(f);
    union { __hip_bfloat16 b; ushort_t u; } c; c.b = h; return c.u;
}
// unpack packed 2xbf16 (low index in low 16 bits)
__device__ __forceinline__ void up2(unsigned u, float& a, float& b){
    a = __uint_as_float(u << 16);
    b = __uint_as_float(u & 0xffff0000u);
}

__device__ __forceinline__ int wstart(int i){
    // L=192, K=7, DIL=3 closed form of _window_starts
    if (i < 9) return i % 3;
    if (i >= 183) return 171 + (i % 3);
    return i - 9;
}

// bf16 row (48 elems, 6 uint4) dot fp32 vec[48]
__device__ __forceinline__ float dot48bf(const uint4* wr, const float* xr){
    float acc = 0.f;
    #pragma unroll
    for (int c8 = 0; c8 < 6; c8++){
        uint4 u = wr[c8];
        float f0,f1,f2,f3,f4,f5,f6,f7;
        up2(u.x,f0,f1); up2(u.y,f2,f3); up2(u.z,f4,f5); up2(u.w,f6,f7);
        acc += f0*xr[8*c8]   + f1*xr[8*c8+1] + f2*xr[8*c8+2] + f3*xr[8*c8+3]
             + f4*xr[8*c8+4] + f5*xr[8*c8+5] + f6*xr[8*c8+6] + f7*xr[8*c8+7];
    }
    return acc;
}

// ------------- Kernel B: convert weights (self-detecting dtype) -----------------
__global__ void convert_kernel(
    const void* p0, const void* p1, const void* p2, const void* p3,
    const void* p4, const void* p5, const void* p6, const void* p7,
    const void* p8, const void* p9, const void* p10, const void* p11,
    const void* p12, const ushort_t* __restrict__ xu, int* __restrict__ mode_out,
    float* __restrict__ wts, ushort_t* __restrict__ qkvbf, float* __restrict__ woutT,
    ushort_t* __restrict__ winbf, ushort_t* __restrict__ projbf)
{
    __shared__ int sbad;
    if (threadIdx.x == 0) sbad = 0;
    __syncthreads();
    {   // 256-sample dtype sniff on x: bf16 N(0,1) never has |v|>=100
        unsigned u = xu[2*threadIdx.x];
        float f = __uint_as_float(u << 16);
        if (!(fabsf(f) < 100.f)) atomicAdd(&sbad, 1);
    }
    __syncthreads();
    const int md = (sbad > 16) ? 1 : 0;
    if (blockIdx.x == 0 && threadIdx.x == 0) mode_out[0] = md;

    const void* ps[13] = {p0,p1,p2,p3,p4,p5,p6,p7,p8,p9,p10,p11,p12};
    const int sz[13]  = {48,48,6912,144,338,2304,48,7,48,48,12192,2286,6096};
    const int off[13] = {O_LN1W,48,O_QKVW,O_QKVB,O_RPB,O_PROJW,O_PROJB,O_ECA,
                         O_LN2W,9897,O_WIN,O_WDW,O_WOUT};
    int b = blockIdx.x;
    if (b >= 13){
        // bf16-packed copies: 13=qkv_w, 14=woutT, 15=w_in, 16=proj_w
        if (b == 13){
            if (md){
                const float* s = (const float*)p2;
                for (int i = threadIdx.x; i < 6912; i += 256) qkvbf[i] = f2u(s[i]);
            } else {
                const ushort_t* s = (const ushort_t*)p2;
                for (int i = threadIdx.x; i < 6912; i += 256) qkvbf[i] = s[i];
            }
        } else if (b == 14){
            if (md){
                const float* s = (const float*)p12;
                for (int i = threadIdx.x; i < 6096; i += 256){
                    int c = i / 48, o = i - c*48;
                    woutT[i] = s[o*127 + c];
                }
            } else {
                const __hip_bfloat16* s = (const __hip_bfloat16*)p12;
                for (int i = threadIdx.x; i < 6096; i += 256){
                    int c = i / 48, o = i - c*48;
                    woutT[i] = b2f(s[o*127 + c]);
                }
            }
        } else if (b == 15){
            if (md){
                const float* s = (const float*)p10;
                for (int i = threadIdx.x; i < 12192; i += 256) winbf[i] = f2u(s[i]);
            } else {
                const ushort_t* s = (const ushort_t*)p10;
                for (int i = threadIdx.x; i < 12192; i += 256) winbf[i] = s[i];
            }
        } else {
            if (md){
                const float* s = (const float*)p5;
                for (int i = threadIdx.x; i < 2304; i += 256) projbf[i] = f2u(s[i]);
            } else {
                const ushort_t* s = (const ushort_t*)p5;
                for (int i = threadIdx.x; i < 2304; i += 256) projbf[i] = s[i];
            }
        }
        return;
    }
    int n = sz[b];
    float* dst = wts + off[b];
    if (md){
        const float* s = (const float*)ps[b];
        for (int i = threadIdx.x; i < n; i += 256) dst[i] = s[i];
    } else {
        const __hip_bfloat16* s = (const __hip_bfloat16*)ps[b];
        for (int i = threadIdx.x; i < n; i += 256) dst[i] = b2f(s[i]);
    }
}

// ------------- Kernel 1: LN1 + QKV proj + ECA partials --------------------------
// 576 blocks x 384 thr = 64 px * 6 wave-uniform r-groups (24 outputs each).
__global__ __launch_bounds__(384) void ln1qkv_kernel(
    const void* __restrict__ x, const int* __restrict__ mode,
    const float* __restrict__ wts, const ushort_t* __restrict__ qkvbf,
    ushort_t* __restrict__ q, ushort_t* __restrict__ k, ushort_t* __restrict__ v,
    float* __restrict__ chpart)
{
    __shared__ float sx[64*49];           // 12544 B

    const int tid  = threadIdx.x;
    const int px_l = tid & 63;
    const int r6   = __builtin_amdgcn_readfirstlane(tid >> 6);  // 0..5 wave-uniform
    const int p0   = blockIdx.x * 64;
    const int p    = p0 + px_l;

    // x tile load, planar-coalesced
    if (mode[0]){
        const float* xf = (const float*)x;
        for (int idx = tid; idx < 64*48; idx += 384){
            int c = idx >> 6, pl = idx & 63;
            sx[pl*49 + c] = xf[c*HW_ + p0 + pl];
        }
    } else {
        const __hip_bfloat16* xb = (const __hip_bfloat16*)x;
        for (int idx = tid; idx < 64*48; idx += 384){
            int c = idx >> 6, pl = idx & 63;
            sx[pl*49 + c] = b2f(xb[c*HW_ + p0 + pl]);
        }
    }
    __syncthreads();

    float xr[48];
    float mu = 0.f;
    #pragma unroll
    for (int c = 0; c < 48; c++){ xr[c] = sx[px_l*49 + c]; mu += xr[c]; }
    mu *= (1.f/48.f);
    float var = 0.f;
    #pragma unroll
    for (int c = 0; c < 48; c++){ float d = xr[c]-mu; var += d*d; }
    var *= (1.f/48.f);
    float rs = rsqrtf(var + 1e-5f);
    #pragma unroll
    for (int c = 0; c < 48; c++)
        xr[c] = (xr[c]-mu)*rs*wts[O_LN1W + c] + wts[O_LN1W + 48 + c];  // scalar K$

    // ECA per-block partials: wave 0 has px 0..63 exactly once
    if (tid < 64){
        #pragma unroll
        for (int c = 0; c < 48; c++){
            float s = xr[c];
            s += __shfl_xor(s, 1);  s += __shfl_xor(s, 2);  s += __shfl_xor(s, 4);
            s += __shfl_xor(s, 8);  s += __shfl_xor(s, 16); s += __shfl_xor(s, 32);
            if (tid == 0) chpart[blockIdx.x*48 + c] = s;
        }
    }

    const int rbase = r6 * 24;
    const float scale = (r6 < 2) ? 0.20412414523193154f : 1.0f;
    float ov[24];
    #pragma unroll 4
    for (int ro = 0; ro < 24; ro++){
        int r = rbase + ro;
        float acc = wts[O_QKVB + r]
                  + dot48bf((const uint4*)(qkvbf + r*48), xr);
        ov[ro] = acc * scale;
    }

    unsigned int pk[12];
    #pragma unroll
    for (int d = 0; d < 12; d++)
        pk[d] = (unsigned)f2u(ov[2*d]) | ((unsigned)f2u(ov[2*d+1]) << 16);
    ushort_t* tp = (r6 >> 1) == 0 ? q : ((r6 >> 1) == 1 ? k : v);
    uint4* dst4 = (uint4*)(tp + (size_t)p*48 + (r6 & 1)*24);
    dst4[0] = make_uint4(pk[0], pk[1], pk[2],  pk[3]);
    dst4[1] = make_uint4(pk[4], pk[5], pk[6],  pk[7]);
    dst4[2] = make_uint4(pk[8], pk[9], pk[10], pk[11]);
}

// ------------- Kernel 2a: parallel partial reduction (48 blocks, 1 per channel) -
__global__ __launch_bounds__(256) void gatered_kernel(
    const float* __restrict__ chpart, float* __restrict__ msum)
{
    __shared__ float red[4];
    const int c = blockIdx.x;          // channel
    const int tid = threadIdx.x;
    float acc = 0.f;
    for (int b = tid; b < NBLK1; b += 256)
        acc += chpart[b*48 + c];
    acc += __shfl_xor(acc, 1);  acc += __shfl_xor(acc, 2);  acc += __shfl_xor(acc, 4);
    acc += __shfl_xor(acc, 8);  acc += __shfl_xor(acc, 16); acc += __shfl_xor(acc, 32);
    if ((tid & 63) == 0) red[tid >> 6] = acc;
    __syncthreads();
    if (tid == 0)
        msum[c] = (red[0] + red[1] + red[2] + red[3]) * (1.f / (float)HW_);
}

// ------------- Kernel 2b: ECA conv1d(k=7,pad=3) -> sigmoid ----------------------
__global__ void gate_kernel(const float* __restrict__ msum,
                            const float* __restrict__ wts,
                            float* __restrict__ gate)
{
    __shared__ float m[48];
    int t = threadIdx.x;
    if (t < 48) m[t] = msum[t];
    __syncthreads();
    if (t < 48){
        float a = 0.f;
        for (int kk = 0; kk < 7; kk++){
            int cc = t + kk - 3;
            if (cc >= 0 && cc < 48) a += wts[O_ECA + kk] * m[cc];
        }
        gate[t] = 1.f / (1.f + expf(-a));
    }
}

// ------------- Kernel 3: neighborhood attention, 4 lanes per (px,head) ----------
// grid (HW/64, 2 heads), block 256: lane = (half: ch 12-split, parity: neighbor
// 2-split). Online softmax per lane over ~25 neighbors; shfl_xor(1) completes the
// 24-ch dot, flash-merge across shfl_xor(2) at the end. 4608 waves -> 18/CU.
__global__ __launch_bounds__(256) void attn_kernel(
    const ushort_t* __restrict__ q, const ushort_t* __restrict__ k,
    const ushort_t* __restrict__ v, const float* __restrict__ wts,
    ushort_t* __restrict__ aout)
{
    const int head = blockIdx.y;
    __shared__ float srpb[169];
    for (int i = threadIdx.x; i < 169; i += 256) srpb[i] = wts[O_RPB + head*169 + i];
    __syncthreads();

    const int tid    = threadIdx.x;
    const int half   = tid & 1;
    const int parity = (tid >> 1) & 1;
    const int px     = blockIdx.x * 64 + (tid >> 2);
    const int i = px / Wd, j = px % Wd;
    const int sti = wstart(i), stj = wstart(j);
    const int pbi = (sti - i) / 3 + 6;
    const int pbj = (stj - j) / 3 + 6;
    const int choff = head*24 + half*12;

    float qr[12];
    {
        const ushort4* qp = (const ushort4*)(q + (size_t)px*48 + choff);
        #pragma unroll
        for (int b = 0; b < 3; b++){
            ushort4 uu = qp[b];
            qr[4*b]   = u2f(uu.x); qr[4*b+1] = u2f(uu.y);
            qr[4*b+2] = u2f(uu.z); qr[4*b+3] = u2f(uu.w);
        }
    }

    float m = -1e30f, s = 0.f;
    float acc[12];
    #pragma unroll
    for (int c = 0; c < 12; c++) acc[c] = 0.f;

    #pragma unroll
    for (int t = 0; t < 25; t++){
        int n = 2*t + parity;
        const bool inval = (n > 48);       // only parity=1, t=24 (processed last)
        if (inval) n = 48;
        int xx = (n * 147) >> 10;          // n/7 for n in [0,48]
        int yy = n - 7*xx;
        int ii = sti + 3*xx, jj = stj + 3*yy;
        const size_t nb = (size_t)(ii*Wd + jj)*48 + choff;
        const ushort4* kp = (const ushort4*)(k + nb);
        const ushort4* vp = (const ushort4*)(v + nb);
        ushort4 k0 = kp[0], k1 = kp[1], k2 = kp[2];
        ushort4 v0 = vp[0], v1 = vp[1], v2 = vp[2];
        float d = qr[0]*u2f(k0.x) + qr[1]*u2f(k0.y)
                + qr[2]*u2f(k0.z) + qr[3]*u2f(k0.w)
                + qr[4]*u2f(k1.x) + qr[5]*u2f(k1.y)
                + qr[6]*u2f(k1.z) + qr[7]*u2f(k1.w)
                + qr[8]*u2f(k2.x) + qr[9]*u2f(k2.y)
                + qr[10]*u2f(k2.z) + qr[11]*u2f(k2.w);
        d += __shfl_xor(d, 1);                         // full 24-ch dot
        float sc = d + srpb[(pbi+xx)*13 + (pbj+yy)];
        if (inval) sc = -1e30f;                        // weight -> exp(-huge) = 0
        float mn = fmaxf(m, sc);
        float corr = __expf(m - mn);
        float p = __expf(sc - mn);
        s = s*corr + p;
        m = mn;
        acc[0]  = acc[0] *corr + p*u2f(v0.x);
        acc[1]  = acc[1] *corr + p*u2f(v0.y);
        acc[2]  = acc[2] *corr + p*u2f(v0.z);
        acc[3]  = acc[3] *corr + p*u2f(v0.w);
        acc[4]  = acc[4] *corr + p*u2f(v1.x);
        acc[5]  = acc[5] *corr + p*u2f(v1.y);
        acc[6]  = acc[6] *corr + p*u2f(v1.z);
        acc[7]  = acc[7] *corr + p*u2f(v1.w);
        acc[8]  = acc[8] *corr + p*u2f(v2.x);
        acc[9]  = acc[9] *corr + p*u2f(v2.y);
        acc[10] = acc[10]*corr + p*u2f(v2.z);
        acc[11] = acc[11]*corr + p*u2f(v2.w);
    }

    // flash-merge the two parity lanes (xor 2): both end with identical state
    {
        float mo = __shfl_xor(m, 2);
        float so = __shfl_xor(s, 2);
        float mn = fmaxf(m, mo);
        float ca = __expf(m - mn), cb = __expf(mo - mn);
        s = s*ca + so*cb;
        #pragma unroll
        for (int c = 0; c < 12; c++)
            acc[c] = acc[c]*ca + __shfl_xor(acc[c], 2)*cb;
    }
    const float inv = 1.f / s;
    if (parity == 0){
        #pragma unroll
        for (int c = 0; c < 12; c++)
            aout[(size_t)(choff + c)*HW_ + px] = f2u(acc[c] * inv);
    }
}

// ------------- Kernel 4: proj + gate + residual -> x2 (no LDS, no sync) ---------
// 576 blocks x 256 thr = 64 px * 4 wave-uniform o-groups (12 outputs each).
__global__ __launch_bounds__(256) void proj_kernel(
    const ushort_t* __restrict__ aout, const float* __restrict__ wts,
    const ushort_t* __restrict__ projbf, const float* __restrict__ gate,
    const void* __restrict__ x, const int* __restrict__ mode,
    float* __restrict__ x2)
{
    const int tid  = threadIdx.x;
    const int px_l = tid & 63;
    const int og   = __builtin_amdgcn_readfirstlane(tid >> 6);   // 0..3 uniform
    const int px   = blockIdx.x * 64 + px_l;

    float ar[48];
    #pragma unroll
    for (int c = 0; c < 48; c++) ar[c] = u2f(aout[(size_t)c*HW_ + px]);

    const float* xf = (const float*)x;
    const __hip_bfloat16* xb = (const __hip_bfloat16*)x;
    const int md = mode[0];
    const int ob = og * 12;
    #pragma unroll 2
    for (int oo = 0; oo < 12; oo++){
        int o = ob + oo;
        float acc = wts[O_PROJB + o]
                  + dot48bf((const uint4*)(projbf + o*48), ar);
        float res = md ? xf[o*HW_ + px] : b2f(xb[o*HW_ + px]);
        x2[o*HW_ + px] = res + acc * gate[o];
    }
}

// ------------- Kernel 5: LN2 (inline) + pointwise1, y-split for occupancy -------
__global__ __launch_bounds__(256) void pw1_kernel(
    const float* __restrict__ x2, const float* __restrict__ wts,
    const ushort_t* __restrict__ winbf, ushort_t* __restrict__ t)
{
    const int tid  = threadIdx.x;
    const int px_l = tid & 63;
    const int og   = __builtin_amdgcn_readfirstlane(tid >> 6);   // 0..3 uniform
    const int px   = blockIdx.x * 64 + px_l;

    float xr[48];
    float mu = 0.f;
    #pragma unroll
    for (int c = 0; c < 48; c++){ xr[c] = x2[c*HW_ + px]; mu += xr[c]; }
    mu *= (1.f/48.f);
    float var = 0.f;
    #pragma unroll
    for (int c = 0; c < 48; c++){ float d = xr[c]-mu; var += d*d; }
    var *= (1.f/48.f);
    float rs = rsqrtf(var + 1e-5f);
    #pragma unroll
    for (int c = 0; c < 48; c++)
        xr[c] = (xr[c]-mu)*rs*wts[O_LN2W + c] + wts[O_LN2W + 48 + c];

    const int base = blockIdx.y * 128 + og * 32;
    for (int t2 = 0; t2 < 32; t2 += 2){
        int o0 = base + t2;
        if (o0 >= 254) break;
        const uint4* wA = (const uint4*)(winbf + o0*48);
        const uint4* wB = (const uint4*)(winbf + min(o0+1,253)*48);
        float accA = 0.f, accB = 0.f;
        #pragma unroll
        for (int c8 = 0; c8 < 6; c8++){
            uint4 ua = wA[c8];
            uint4 ub = wB[c8];
            float a0,a1,a2,a3,a4,a5,a6,a7, b0,b1,b2,b3,b4,b5,b6,b7;
            up2(ua.x,a0,a1); up2(ua.y,a2,a3); up2(ua.z,a4,a5); up2(ua.w,a6,a7);
            up2(ub.x,b0,b1); up2(ub.y,b2,b3); up2(ub.z,b4,b5); up2(ub.w,b6,b7);
            accA += a0*xr[8*c8]   + a1*xr[8*c8+1] + a2*xr[8*c8+2] + a3*xr[8*c8+3]
                  + a4*xr[8*c8+4] + a5*xr[8*c8+5] + a6*xr[8*c8+6] + a7*xr[8*c8+7];
            accB += b0*xr[8*c8]   + b1*xr[8*c8+1] + b2*xr[8*c8+2] + b3*xr[8*c8+3]
                  + b4*xr[8*c8+4] + b5*xr[8*c8+5] + b6*xr[8*c8+6] + b7*xr[8*c8+7];
        }
        t[(size_t)o0*HW_ + px] = f2u(accA);
        if (o0+1 < 254) t[(size_t)(o0+1)*HW_ + px] = f2u(accB);
    }
}

// ------------- Kernel 6: depthwise 3x3 + exact GeLU gating, bf16 in/out ---------
__global__ __launch_bounds__(256) void dw_kernel(
    const ushort_t* __restrict__ t, const float* __restrict__ wts,
    ushort_t* __restrict__ g)
{
    int ch = blockIdx.y;               // 0..126
    int p  = blockIdx.x * 256 + threadIdx.x;
    int i  = p / Wd, j = p % Wd;
    float w1[9], w2[9];
    #pragma unroll
    for (int s = 0; s < 9; s++){
        w1[s] = wts[O_WDW + ch*9 + s];
        w2[s] = wts[O_WDW + (ch+HIDc)*9 + s];
    }
    const ushort_t* t1 = t + (size_t)ch * HW_;
    const ushort_t* t2 = t + (size_t)(ch+HIDc) * HW_;
    float a1 = 0.f, a2 = 0.f;
    #pragma unroll
    for (int di = 0; di < 3; di++){
        int ii = i + di - 1;
        if (ii < 0 || ii >= 192) continue;
        #pragma unroll
        for (int dj = 0; dj < 3; dj++){
            int jj = j + dj - 1;
            if (jj < 0 || jj >= 192) continue;
            int off = ii*Wd + jj;
            a1 += w1[di*3+dj]*u2f(t1[off]);
            a2 += w2[di*3+dj]*u2f(t2[off]);
        }
    }
    float ge = a1 * 0.5f * (1.f + erff(a1 * 0.70710678118654752f)); // exact gelu
    g[(size_t)ch*HW_ + p] = f2u(ge * a2);
}

// ------------- Kernel 7: pointwise2 (woutT scalar-K$) + final residual ----------
__global__ __launch_bounds__(128) void pw2_kernel(
    const ushort_t* __restrict__ g, const float* __restrict__ woutT,
    const float* __restrict__ x2, void* __restrict__ outv,
    const int* __restrict__ mode)
{
    const int ob = blockIdx.y * 12;
    const int p  = blockIdx.x * 128 + threadIdx.x;
    float acc[12];
    #pragma unroll
    for (int o = 0; o < 12; o++) acc[o] = 0.f;
    #pragma unroll 4
    for (int c = 0; c < 127; c++){
        float gv = u2f(g[(size_t)c*HW_ + p]);
        const float* wr = woutT + c*48 + ob;          // uniform -> s_load
        #pragma unroll
        for (int o = 0; o < 12; o++) acc[o] += wr[o]*gv;
    }
    if (mode[0]){
        float* out = (float*)outv;
        #pragma unroll
        for (int o = 0; o < 12; o++){
            int oc = ob + o;
            out[(size_t)oc*HW_ + p] = x2[(size_t)oc*HW_ + p] + acc[o];
        }
    } else {
        __hip_bfloat16* out = (__hip_bfloat16*)outv;
        #pragma unroll
        for (int o = 0; o < 12; o++){
            int oc = ob + o;
            out[(size_t)oc*HW_ + p] =
                __float2bfloat16(x2[(size_t)oc*HW_ + p] + acc[o]);
        }
    }
}

extern "C" void kernel_launch(void* const* d_in, const int* in_sizes, int n_in,
                              void* d_out, int out_size, void* d_ws, size_t ws_size,
                              hipStream_t stream)
{
    (void)in_sizes; (void)n_in; (void)out_size;

    char* ws = (char*)d_ws;
    ushort_t* q    = (ushort_t*)(ws);
    ushort_t* k    = (ushort_t*)(ws + 3538944);
    ushort_t* v    = (ushort_t*)(ws + 7077888);
    ushort_t* aout = (ushort_t*)(ws + 10616832);
    ushort_t* t    = (ushort_t*)(ws);
    float*    x2   = (float*)   (ws + 18726912);
    ushort_t* g    = (ushort_t*)(ws + 25804800);
    float*    gate = (float*)   (ws + 35168448);
    int*      mode = (int*)     (ws + 35168640);
    float*    wts  = (float*)   (ws + 35168656);
    float*    chpart=(float*)   (ws + 35168656 + (size_t)WTS_LEN*4); // [NBLK1][48]
    float*    msum = chpart + (size_t)NBLK1*48;                      // [48]
    ushort_t* qkvbf= (ushort_t*)(msum + 48);                         // [6912] bf16
    float*    woutT= (float*)(qkvbf + 6912);                         // [127*48]
    ushort_t* winbf= (ushort_t*)(woutT + 6096);                      // [12192] bf16
    ushort_t* projbf=(ushort_t*)(winbf + 12192);                     // [2304] bf16

    size_t need = 35168656 + (size_t)WTS_LEN*4 + (size_t)NBLK1*48*4 + 48*4
                + 6912*2 + 6096*4 + 12192*2 + 2304*2;
    if (ws_size < need) return;

    convert_kernel<<<17, 256, 0, stream>>>(
        d_in[1], d_in[2], d_in[3], d_in[4], d_in[5], d_in[6], d_in[7],
        d_in[8], d_in[9], d_in[10], d_in[11], d_in[12], d_in[13],
        (const ushort_t*)d_in[0], mode, wts, qkvbf, woutT, winbf, projbf);

    ln1qkv_kernel<<<dim3(NBLK1), 384, 0, stream>>>(d_in[0], mode, wts, qkvbf,
                                                   q, k, v, chpart);
    gatered_kernel<<<48, 256, 0, stream>>>(chpart, msum);
    gate_kernel<<<1, 64, 0, stream>>>(msum, wts, gate);
    attn_kernel<<<dim3(HW_/64, 2), 256, 0, stream>>>(q, k, v, wts, aout);
    proj_kernel<<<dim3(HW_/64), 256, 0, stream>>>(aout, wts, projbf, gate,
                                                  d_in[0], mode, x2);
    pw1_kernel<<<dim3(HW_/64, 2), 256, 0, stream>>>(x2, wts, winbf, t);
    dw_kernel<<<dim3(HW_/256, 127), 256, 0, stream>>>(t, wts, g);
    pw2_kernel<<<dim3(HW_/128, 4), 128, 0, stream>>>(g, woutT, x2, d_out, mode);
}

// Round 16
// 247.963 us; speedup vs baseline: 1.0775x; 1.0336x over previous
//
#include <hip/hip_runtime.h>
#include <hip/hip_bf16.h>
#include <math.h>

#define HW_ (192*192)
#define Wd 192
#define HIDc 127
#define NBLK1 (HW_/64)   // 576 ln1qkv blocks

// fp32 weight-copy offsets inside ws "wts" region
#define O_LN1W 0
#define O_QKVW 96
#define O_QKVB 7008
#define O_RPB  7152
#define O_PROJW 7490
#define O_PROJB 9794
#define O_ECA  9842
#define O_LN2W 9849
#define O_WIN  9945
#define O_WDW  22137
#define O_WOUT 24423
#define WTS_LEN 30519

typedef unsigned short ushort_t;

__device__ __forceinline__ float b2f(__hip_bfloat16 v){ return __bfloat162float(v); }
__device__ __forceinline__ float u2f(ushort_t h){ return __uint_as_float(((unsigned)h)<<16); }
__device__ __forceinline__ ushort_t f2u(float f){
    __hip_bfloat16 h = __float2bfloat16(f);
    union { __hip_bfloat16 b; ushort_t u; } c; c.b = h; return c.u;
}
// unpack packed 2xbf16 (low index in low 16 bits)
__device__ __forceinline__ void up2(unsigned u, float& a, float& b){
    a = __uint_as_float(u << 16);
    b = __uint_as_float(u & 0xffff0000u);
}

__device__ __forceinline__ int wstart(int i){
    // L=192, K=7, DIL=3 closed form of _window_starts
    if (i < 9) return i % 3;
    if (i >= 183) return 171 + (i % 3);
    return i - 9;
}

// bf16 row (48 elems, 6 uint4) dot fp32 vec[48]
__device__ __forceinline__ float dot48bf(const uint4* wr, const float* xr){
    float acc = 0.f;
    #pragma unroll
    for (int c8 = 0; c8 < 6; c8++){
        uint4 u = wr[c8];
        float f0,f1,f2,f3,f4,f5,f6,f7;
        up2(u.x,f0,f1); up2(u.y,f2,f3); up2(u.z,f4,f5); up2(u.w,f6,f7);
        acc += f0*xr[8*c8]   + f1*xr[8*c8+1] + f2*xr[8*c8+2] + f3*xr[8*c8+3]
             + f4*xr[8*c8+4] + f5*xr[8*c8+5] + f6*xr[8*c8+6] + f7*xr[8*c8+7];
    }
    return acc;
}

// ------------- Kernel B: convert weights (self-detecting dtype) -----------------
__global__ void convert_kernel(
    const void* p0, const void* p1, const void* p2, const void* p3,
    const void* p4, const void* p5, const void* p6, const void* p7,
    const void* p8, const void* p9, const void* p10, const void* p11,
    const void* p12, const ushort_t* __restrict__ xu, int* __restrict__ mode_out,
    float* __restrict__ wts, ushort_t* __restrict__ qkvbf, ushort_t* __restrict__ woutTbf,
    ushort_t* __restrict__ winbf, ushort_t* __restrict__ projbf)
{
    __shared__ int sbad;
    if (threadIdx.x == 0) sbad = 0;
    __syncthreads();
    {   // 256-sample dtype sniff on x: bf16 N(0,1) never has |v|>=100
        unsigned u = xu[2*threadIdx.x];
        float f = __uint_as_float(u << 16);
        if (!(fabsf(f) < 100.f)) atomicAdd(&sbad, 1);
    }
    __syncthreads();
    const int md = (sbad > 16) ? 1 : 0;
    if (blockIdx.x == 0 && threadIdx.x == 0) mode_out[0] = md;

    const void* ps[13] = {p0,p1,p2,p3,p4,p5,p6,p7,p8,p9,p10,p11,p12};
    const int sz[13]  = {48,48,6912,144,338,2304,48,7,48,48,12192,2286,6096};
    const int off[13] = {O_LN1W,48,O_QKVW,O_QKVB,O_RPB,O_PROJW,O_PROJB,O_ECA,
                         O_LN2W,9897,O_WIN,O_WDW,O_WOUT};
    int b = blockIdx.x;
    if (b >= 13){
        // bf16-packed copies: 13=qkv_w, 14=woutT (transposed), 15=w_in, 16=proj_w
        if (b == 13){
            if (md){
                const float* s = (const float*)p2;
                for (int i = threadIdx.x; i < 6912; i += 256) qkvbf[i] = f2u(s[i]);
            } else {
                const ushort_t* s = (const ushort_t*)p2;
                for (int i = threadIdx.x; i < 6912; i += 256) qkvbf[i] = s[i];
            }
        } else if (b == 14){
            if (md){
                const float* s = (const float*)p12;
                for (int i = threadIdx.x; i < 6096; i += 256){
                    int c = i / 48, o = i - c*48;
                    woutTbf[i] = f2u(s[o*127 + c]);
                }
            } else {
                const ushort_t* s = (const ushort_t*)p12;
                for (int i = threadIdx.x; i < 6096; i += 256){
                    int c = i / 48, o = i - c*48;
                    woutTbf[i] = s[o*127 + c];
                }
            }
        } else if (b == 15){
            if (md){
                const float* s = (const float*)p10;
                for (int i = threadIdx.x; i < 12192; i += 256) winbf[i] = f2u(s[i]);
            } else {
                const ushort_t* s = (const ushort_t*)p10;
                for (int i = threadIdx.x; i < 12192; i += 256) winbf[i] = s[i];
            }
        } else {
            if (md){
                const float* s = (const float*)p5;
                for (int i = threadIdx.x; i < 2304; i += 256) projbf[i] = f2u(s[i]);
            } else {
                const ushort_t* s = (const ushort_t*)p5;
                for (int i = threadIdx.x; i < 2304; i += 256) projbf[i] = s[i];
            }
        }
        return;
    }
    int n = sz[b];
    float* dst = wts + off[b];
    if (md){
        const float* s = (const float*)ps[b];
        for (int i = threadIdx.x; i < n; i += 256) dst[i] = s[i];
    } else {
        const __hip_bfloat16* s = (const __hip_bfloat16*)ps[b];
        for (int i = threadIdx.x; i < n; i += 256) dst[i] = b2f(s[i]);
    }
}

// ------------- Kernel 1: LN1 + QKV proj + ECA partials --------------------------
// 576 blocks x 384 thr = 64 px * 6 wave-uniform r-groups (24 outputs each).
__global__ __launch_bounds__(384) void ln1qkv_kernel(
    const void* __restrict__ x, const int* __restrict__ mode,
    const float* __restrict__ wts, const ushort_t* __restrict__ qkvbf,
    ushort_t* __restrict__ q, ushort_t* __restrict__ k, ushort_t* __restrict__ v,
    float* __restrict__ chpart)
{
    __shared__ float sx[64*49];           // 12544 B

    const int tid  = threadIdx.x;
    const int px_l = tid & 63;
    const int r6   = __builtin_amdgcn_readfirstlane(tid >> 6);  // 0..5 wave-uniform
    const int p0   = blockIdx.x * 64;
    const int p    = p0 + px_l;

    // x tile load, planar-coalesced
    if (mode[0]){
        const float* xf = (const float*)x;
        for (int idx = tid; idx < 64*48; idx += 384){
            int c = idx >> 6, pl = idx & 63;
            sx[pl*49 + c] = xf[c*HW_ + p0 + pl];
        }
    } else {
        const __hip_bfloat16* xb = (const __hip_bfloat16*)x;
        for (int idx = tid; idx < 64*48; idx += 384){
            int c = idx >> 6, pl = idx & 63;
            sx[pl*49 + c] = b2f(xb[c*HW_ + p0 + pl]);
        }
    }
    __syncthreads();

    float xr[48];
    float mu = 0.f;
    #pragma unroll
    for (int c = 0; c < 48; c++){ xr[c] = sx[px_l*49 + c]; mu += xr[c]; }
    mu *= (1.f/48.f);
    float var = 0.f;
    #pragma unroll
    for (int c = 0; c < 48; c++){ float d = xr[c]-mu; var += d*d; }
    var *= (1.f/48.f);
    float rs = rsqrtf(var + 1e-5f);
    #pragma unroll
    for (int c = 0; c < 48; c++)
        xr[c] = (xr[c]-mu)*rs*wts[O_LN1W + c] + wts[O_LN1W + 48 + c];  // scalar K$

    // ECA per-block partials: wave 0 has px 0..63 exactly once
    if (tid < 64){
        #pragma unroll
        for (int c = 0; c < 48; c++){
            float s = xr[c];
            s += __shfl_xor(s, 1);  s += __shfl_xor(s, 2);  s += __shfl_xor(s, 4);
            s += __shfl_xor(s, 8);  s += __shfl_xor(s, 16); s += __shfl_xor(s, 32);
            if (tid == 0) chpart[blockIdx.x*48 + c] = s;
        }
    }

    const int rbase = r6 * 24;
    const float scale = (r6 < 2) ? 0.20412414523193154f : 1.0f;
    float ov[24];
    #pragma unroll 4
    for (int ro = 0; ro < 24; ro++){
        int r = rbase + ro;
        float acc = wts[O_QKVB + r]
                  + dot48bf((const uint4*)(qkvbf + r*48), xr);
        ov[ro] = acc * scale;
    }

    unsigned int pk[12];
    #pragma unroll
    for (int d = 0; d < 12; d++)
        pk[d] = (unsigned)f2u(ov[2*d]) | ((unsigned)f2u(ov[2*d+1]) << 16);
    ushort_t* tp = (r6 >> 1) == 0 ? q : ((r6 >> 1) == 1 ? k : v);
    uint4* dst4 = (uint4*)(tp + (size_t)p*48 + (r6 & 1)*24);
    dst4[0] = make_uint4(pk[0], pk[1], pk[2],  pk[3]);
    dst4[1] = make_uint4(pk[4], pk[5], pk[6],  pk[7]);
    dst4[2] = make_uint4(pk[8], pk[9], pk[10], pk[11]);
}

// ------------- Kernel 2a: parallel partial reduction (48 blocks, 1 per channel) -
__global__ __launch_bounds__(256) void gatered_kernel(
    const float* __restrict__ chpart, float* __restrict__ msum)
{
    __shared__ float red[4];
    const int c = blockIdx.x;          // channel
    const int tid = threadIdx.x;
    float acc = 0.f;
    for (int b = tid; b < NBLK1; b += 256)
        acc += chpart[b*48 + c];
    acc += __shfl_xor(acc, 1);  acc += __shfl_xor(acc, 2);  acc += __shfl_xor(acc, 4);
    acc += __shfl_xor(acc, 8);  acc += __shfl_xor(acc, 16); acc += __shfl_xor(acc, 32);
    if ((tid & 63) == 0) red[tid >> 6] = acc;
    __syncthreads();
    if (tid == 0)
        msum[c] = (red[0] + red[1] + red[2] + red[3]) * (1.f / (float)HW_);
}

// ------------- Kernel 2b: ECA conv1d(k=7,pad=3) -> sigmoid ----------------------
__global__ void gate_kernel(const float* __restrict__ msum,
                            const float* __restrict__ wts,
                            float* __restrict__ gate)
{
    __shared__ float m[48];
    int t = threadIdx.x;
    if (t < 48) m[t] = msum[t];
    __syncthreads();
    if (t < 48){
        float a = 0.f;
        for (int kk = 0; kk < 7; kk++){
            int cc = t + kk - 3;
            if (cc >= 0 && cc < 48) a += wts[O_ECA + kk] * m[cc];
        }
        gate[t] = 1.f / (1.f + expf(-a));
    }
}

// ------------- Kernel 3: neighborhood attention, 4 lanes per (px,head) ----------
__global__ __launch_bounds__(256) void attn_kernel(
    const ushort_t* __restrict__ q, const ushort_t* __restrict__ k,
    const ushort_t* __restrict__ v, const float* __restrict__ wts,
    ushort_t* __restrict__ aout)
{
    const int head = blockIdx.y;
    __shared__ float srpb[169];
    for (int i = threadIdx.x; i < 169; i += 256) srpb[i] = wts[O_RPB + head*169 + i];
    __syncthreads();

    const int tid    = threadIdx.x;
    const int half   = tid & 1;
    const int parity = (tid >> 1) & 1;
    const int px     = blockIdx.x * 64 + (tid >> 2);
    const int i = px / Wd, j = px % Wd;
    const int sti = wstart(i), stj = wstart(j);
    const int pbi = (sti - i) / 3 + 6;
    const int pbj = (stj - j) / 3 + 6;
    const int choff = head*24 + half*12;

    float qr[12];
    {
        const ushort4* qp = (const ushort4*)(q + (size_t)px*48 + choff);
        #pragma unroll
        for (int b = 0; b < 3; b++){
            ushort4 uu = qp[b];
            qr[4*b]   = u2f(uu.x); qr[4*b+1] = u2f(uu.y);
            qr[4*b+2] = u2f(uu.z); qr[4*b+3] = u2f(uu.w);
        }
    }

    float m = -1e30f, s = 0.f;
    float acc[12];
    #pragma unroll
    for (int c = 0; c < 12; c++) acc[c] = 0.f;

    #pragma unroll
    for (int t = 0; t < 25; t++){
        int n = 2*t + parity;
        const bool inval = (n > 48);       // only parity=1, t=24 (processed last)
        if (inval) n = 48;
        int xx = (n * 147) >> 10;          // n/7 for n in [0,48]
        int yy = n - 7*xx;
        int ii = sti + 3*xx, jj = stj + 3*yy;
        const size_t nb = (size_t)(ii*Wd + jj)*48 + choff;
        const ushort4* kp = (const ushort4*)(k + nb);
        const ushort4* vp = (const ushort4*)(v + nb);
        ushort4 k0 = kp[0], k1 = kp[1], k2 = kp[2];
        ushort4 v0 = vp[0], v1 = vp[1], v2 = vp[2];
        float d = qr[0]*u2f(k0.x) + qr[1]*u2f(k0.y)
                + qr[2]*u2f(k0.z) + qr[3]*u2f(k0.w)
                + qr[4]*u2f(k1.x) + qr[5]*u2f(k1.y)
                + qr[6]*u2f(k1.z) + qr[7]*u2f(k1.w)
                + qr[8]*u2f(k2.x) + qr[9]*u2f(k2.y)
                + qr[10]*u2f(k2.z) + qr[11]*u2f(k2.w);
        d += __shfl_xor(d, 1);                         // full 24-ch dot
        float sc = d + srpb[(pbi+xx)*13 + (pbj+yy)];
        if (inval) sc = -1e30f;                        // weight -> exp(-huge) = 0
        float mn = fmaxf(m, sc);
        float corr = __expf(m - mn);
        float p = __expf(sc - mn);
        s = s*corr + p;
        m = mn;
        acc[0]  = acc[0] *corr + p*u2f(v0.x);
        acc[1]  = acc[1] *corr + p*u2f(v0.y);
        acc[2]  = acc[2] *corr + p*u2f(v0.z);
        acc[3]  = acc[3] *corr + p*u2f(v0.w);
        acc[4]  = acc[4] *corr + p*u2f(v1.x);
        acc[5]  = acc[5] *corr + p*u2f(v1.y);
        acc[6]  = acc[6] *corr + p*u2f(v1.z);
        acc[7]  = acc[7] *corr + p*u2f(v1.w);
        acc[8]  = acc[8] *corr + p*u2f(v2.x);
        acc[9]  = acc[9] *corr + p*u2f(v2.y);
        acc[10] = acc[10]*corr + p*u2f(v2.z);
        acc[11] = acc[11]*corr + p*u2f(v2.w);
    }

    // flash-merge the two parity lanes (xor 2): both end with identical state
    {
        float mo = __shfl_xor(m, 2);
        float so = __shfl_xor(s, 2);
        float mn = fmaxf(m, mo);
        float ca = __expf(m - mn), cb = __expf(mo - mn);
        s = s*ca + so*cb;
        #pragma unroll
        for (int c = 0; c < 12; c++)
            acc[c] = acc[c]*ca + __shfl_xor(acc[c], 2)*cb;
    }
    const float inv = 1.f / s;
    if (parity == 0){
        #pragma unroll
        for (int c = 0; c < 12; c++)
            aout[(size_t)(choff + c)*HW_ + px] = f2u(acc[c] * inv);
    }
}

// ------------- Kernel 4: proj + gate + residual -> x2 (no LDS, no sync) ---------
__global__ __launch_bounds__(256) void proj_kernel(
    const ushort_t* __restrict__ aout, const float* __restrict__ wts,
    const ushort_t* __restrict__ projbf, const float* __restrict__ gate,
    const void* __restrict__ x, const int* __restrict__ mode,
    float* __restrict__ x2)
{
    const int tid  = threadIdx.x;
    const int px_l = tid & 63;
    const int og   = __builtin_amdgcn_readfirstlane(tid >> 6);   // 0..3 uniform
    const int px   = blockIdx.x * 64 + px_l;

    float ar[48];
    #pragma unroll
    for (int c = 0; c < 48; c++) ar[c] = u2f(aout[(size_t)c*HW_ + px]);

    const float* xf = (const float*)x;
    const __hip_bfloat16* xb = (const __hip_bfloat16*)x;
    const int md = mode[0];
    const int ob = og * 12;
    #pragma unroll 2
    for (int oo = 0; oo < 12; oo++){
        int o = ob + oo;
        float acc = wts[O_PROJB + o]
                  + dot48bf((const uint4*)(projbf + o*48), ar);
        float res = md ? xf[o*HW_ + px] : b2f(xb[o*HW_ + px]);
        x2[o*HW_ + px] = res + acc * gate[o];
    }
}

// ------------- Kernel 5: LN2 (inline) + pointwise1, y-split for occupancy -------
__global__ __launch_bounds__(256) void pw1_kernel(
    const float* __restrict__ x2, const float* __restrict__ wts,
    const ushort_t* __restrict__ winbf, ushort_t* __restrict__ t)
{
    const int tid  = threadIdx.x;
    const int px_l = tid & 63;
    const int og   = __builtin_amdgcn_readfirstlane(tid >> 6);   // 0..3 uniform
    const int px   = blockIdx.x * 64 + px_l;

    float xr[48];
    float mu = 0.f;
    #pragma unroll
    for (int c = 0; c < 48; c++){ xr[c] = x2[c*HW_ + px]; mu += xr[c]; }
    mu *= (1.f/48.f);
    float var = 0.f;
    #pragma unroll
    for (int c = 0; c < 48; c++){ float d = xr[c]-mu; var += d*d; }
    var *= (1.f/48.f);
    float rs = rsqrtf(var + 1e-5f);
    #pragma unroll
    for (int c = 0; c < 48; c++)
        xr[c] = (xr[c]-mu)*rs*wts[O_LN2W + c] + wts[O_LN2W + 48 + c];

    const int base = blockIdx.y * 128 + og * 32;
    for (int t2 = 0; t2 < 32; t2 += 2){
        int o0 = base + t2;
        if (o0 >= 254) break;
        const uint4* wA = (const uint4*)(winbf + o0*48);
        const uint4* wB = (const uint4*)(winbf + min(o0+1,253)*48);
        float accA = 0.f, accB = 0.f;
        #pragma unroll
        for (int c8 = 0; c8 < 6; c8++){
            uint4 ua = wA[c8];
            uint4 ub = wB[c8];
            float a0,a1,a2,a3,a4,a5,a6,a7, b0,b1,b2,b3,b4,b5,b6,b7;
            up2(ua.x,a0,a1); up2(ua.y,a2,a3); up2(ua.z,a4,a5); up2(ua.w,a6,a7);
            up2(ub.x,b0,b1); up2(ub.y,b2,b3); up2(ub.z,b4,b5); up2(ub.w,b6,b7);
            accA += a0*xr[8*c8]   + a1*xr[8*c8+1] + a2*xr[8*c8+2] + a3*xr[8*c8+3]
                  + a4*xr[8*c8+4] + a5*xr[8*c8+5] + a6*xr[8*c8+6] + a7*xr[8*c8+7];
            accB += b0*xr[8*c8]   + b1*xr[8*c8+1] + b2*xr[8*c8+2] + b3*xr[8*c8+3]
                  + b4*xr[8*c8+4] + b5*xr[8*c8+5] + b6*xr[8*c8+6] + b7*xr[8*c8+7];
        }
        t[(size_t)o0*HW_ + px] = f2u(accA);
        if (o0+1 < 254) t[(size_t)(o0+1)*HW_ + px] = f2u(accB);
    }
}

// ------------- Kernel 6: depthwise 3x3 + GeLU gating, 2 px/thread ---------------
// grid (HW/512, 127), block 256: each thread computes an even-aligned px pair.
__global__ __launch_bounds__(256) void dw_kernel(
    const ushort_t* __restrict__ t, const float* __restrict__ wts,
    ushort_t* __restrict__ g)
{
    const int ch = blockIdx.y;               // 0..126
    const int pp = (blockIdx.x * 256 + threadIdx.x) * 2;   // even px
    const int i  = pp / Wd, j = pp % Wd;     // j even, pair never crosses a row
    float w1[9], w2[9];
    #pragma unroll
    for (int s = 0; s < 9; s++){
        w1[s] = wts[O_WDW + ch*9 + s];
        w2[s] = wts[O_WDW + (ch+HIDc)*9 + s];
    }
    const ushort_t* t1 = t + (size_t)ch * HW_;
    const ushort_t* t2 = t + (size_t)(ch+HIDc) * HW_;
    float a1x = 0.f, a1y = 0.f, a2x = 0.f, a2y = 0.f;
    #pragma unroll
    for (int di = 0; di < 3; di++){
        int ii = i + di - 1;
        if (ii < 0 || ii >= 192) continue;
        int base = ii*Wd + j;
        // row values at columns j-1, j, j+1, j+2 (zero at borders)
        float r0 = (j   > 0)   ? u2f(t1[base-1]) : 0.f;
        float r1 = u2f(t1[base]);
        float r2 = u2f(t1[base+1]);
        float r3 = (j+2 < 192) ? u2f(t1[base+2]) : 0.f;
        float s0 = (j   > 0)   ? u2f(t2[base-1]) : 0.f;
        float s1 = u2f(t2[base]);
        float s2 = u2f(t2[base+1]);
        float s3 = (j+2 < 192) ? u2f(t2[base+2]) : 0.f;
        float wa = w1[di*3], wb = w1[di*3+1], wc = w1[di*3+2];
        a1x += wa*r0 + wb*r1 + wc*r2;
        a1y += wa*r1 + wb*r2 + wc*r3;
        wa = w2[di*3]; wb = w2[di*3+1]; wc = w2[di*3+2];
        a2x += wa*s0 + wb*s1 + wc*s2;
        a2y += wa*s1 + wb*s2 + wc*s3;
    }
    float gx = a1x * 0.5f * (1.f + erff(a1x * 0.70710678118654752f)) * a2x;
    float gy = a1y * 0.5f * (1.f + erff(a1y * 0.70710678118654752f)) * a2y;
    unsigned pk = (unsigned)f2u(gx) | ((unsigned)f2u(gy) << 16);
    *(unsigned*)(g + (size_t)ch*HW_ + pp) = pk;      // pp even -> 4B aligned
}

// ------------- Kernel 7: pointwise2 (bf16 woutT via scalar K$) + residual -------
__global__ __launch_bounds__(128) void pw2_kernel(
    const ushort_t* __restrict__ g, const ushort_t* __restrict__ woutTbf,
    const float* __restrict__ x2, void* __restrict__ outv,
    const int* __restrict__ mode)
{
    const int ob = blockIdx.y * 12;
    const int p  = blockIdx.x * 128 + threadIdx.x;
    float acc[12];
    #pragma unroll
    for (int o = 0; o < 12; o++) acc[o] = 0.f;
    #pragma unroll 4
    for (int c = 0; c < 127; c++){
        float gv = u2f(g[(size_t)c*HW_ + p]);
        // 12 bf16 weights, uniform address (8B-aligned) -> s_load
        const unsigned* wr = (const unsigned*)(woutTbf + c*48 + ob);
        #pragma unroll
        for (int d = 0; d < 6; d++){
            float w0, w1;
            up2(wr[d], w0, w1);
            acc[2*d]   += w0*gv;
            acc[2*d+1] += w1*gv;
        }
    }
    if (mode[0]){
        float* out = (float*)outv;
        #pragma unroll
        for (int o = 0; o < 12; o++){
            int oc = ob + o;
            out[(size_t)oc*HW_ + p] = x2[(size_t)oc*HW_ + p] + acc[o];
        }
    } else {
        __hip_bfloat16* out = (__hip_bfloat16*)outv;
        #pragma unroll
        for (int o = 0; o < 12; o++){
            int oc = ob + o;
            out[(size_t)oc*HW_ + p] =
                __float2bfloat16(x2[(size_t)oc*HW_ + p] + acc[o]);
        }
    }
}

extern "C" void kernel_launch(void* const* d_in, const int* in_sizes, int n_in,
                              void* d_out, int out_size, void* d_ws, size_t ws_size,
                              hipStream_t stream)
{
    (void)in_sizes; (void)n_in; (void)out_size;

    char* ws = (char*)d_ws;
    ushort_t* q    = (ushort_t*)(ws);
    ushort_t* k    = (ushort_t*)(ws + 3538944);
    ushort_t* v    = (ushort_t*)(ws + 7077888);
    ushort_t* aout = (ushort_t*)(ws + 10616832);
    ushort_t* t    = (ushort_t*)(ws);
    float*    x2   = (float*)   (ws + 18726912);
    ushort_t* g    = (ushort_t*)(ws + 25804800);
    float*    gate = (float*)   (ws + 35168448);
    int*      mode = (int*)     (ws + 35168640);
    float*    wts  = (float*)   (ws + 35168656);
    float*    chpart=(float*)   (ws + 35168656 + (size_t)WTS_LEN*4); // [NBLK1][48]
    float*    msum = chpart + (size_t)NBLK1*48;                      // [48]
    ushort_t* qkvbf= (ushort_t*)(msum + 48);                         // [6912] bf16
    ushort_t* woutTbf = qkvbf + 6912;                                // [6096] bf16
    ushort_t* winbf   = woutTbf + 6096;                              // [12192] bf16
    ushort_t* projbf  = winbf + 12192;                               // [2304] bf16

    size_t need = 35168656 + (size_t)WTS_LEN*4 + (size_t)NBLK1*48*4 + 48*4
                + (6912 + 6096 + 12192 + 2304)*2;
    if (ws_size < need) return;

    convert_kernel<<<17, 256, 0, stream>>>(
        d_in[1], d_in[2], d_in[3], d_in[4], d_in[5], d_in[6], d_in[7],
        d_in[8], d_in[9], d_in[10], d_in[11], d_in[12], d_in[13],
        (const ushort_t*)d_in[0], mode, wts, qkvbf, woutTbf, winbf, projbf);

    ln1qkv_kernel<<<dim3(NBLK1), 384, 0, stream>>>(d_in[0], mode, wts, qkvbf,
                                                   q, k, v, chpart);
    gatered_kernel<<<48, 256, 0, stream>>>(chpart, msum);
    gate_kernel<<<1, 64, 0, stream>>>(msum, wts, gate);
    attn_kernel<<<dim3(HW_/64, 2), 256, 0, stream>>>(q, k, v, wts, aout);
    proj_kernel<<<dim3(HW_/64), 256, 0, stream>>>(aout, wts, projbf, gate,
                                                  d_in[0], mode, x2);
    pw1_kernel<<<dim3(HW_/64, 2), 256, 0, stream>>>(x2, wts, winbf, t);
    dw_kernel<<<dim3(HW_/512, 127), 256, 0, stream>>>(t, wts, g);
    pw2_kernel<<<dim3(HW_/128, 4), 128, 0, stream>>>(g, woutTbf, x2, d_out, mode);
}